// Round 3
// baseline (3527.621 us; speedup 1.0000x reference)
//
#include <hip/hip_runtime.h>

#define B_ROWS 16384
#define D_DIM  2048
#define H_DIM  512
#define BM     32
#define BN     64
#define BK     32
#define CHUNKS (H_DIM / BN)   // 8
#define KTILES (D_DIM / BK)   // 64
#define PAD_AT 34

// ---------------------------------------------------------------------------
// q0 = gw0 @ Wq + bq   ->  d_ws[0..511]
// ---------------------------------------------------------------------------
__global__ void q0_kernel(const float* __restrict__ gw0,
                          const float* __restrict__ Wq,
                          const float* __restrict__ bq,
                          float* __restrict__ q0out) {
    __shared__ float red[256];
    const int c  = blockIdx.x * 16 + (threadIdx.x & 15);
    const int dq = threadIdx.x >> 4;           // 0..15
    float s = 0.f;
#pragma unroll 8
    for (int i = 0; i < 128; ++i) {
        const int d = dq * 128 + i;
        s = fmaf(gw0[d], Wq[(size_t)d * H_DIM + c], s);
    }
    red[threadIdx.x] = s;
    __syncthreads();
    if (threadIdx.x < 16) {
        float t = 0.f;
#pragma unroll
        for (int q = 0; q < 16; ++q) t += red[q * 16 + threadIdx.x];
        q0out[c] = t + bq[c];
    }
}

// ---------------------------------------------------------------------------
// Fused: K_v,K_t,P_v,P_t tile-GEMMs -> 8 per-row scalars -> 4-step recurrence
// ---------------------------------------------------------------------------
__global__ __launch_bounds__(256, 2)
void dqa_kernel(const float* __restrict__ x_v, const float* __restrict__ x_t,
                const float* __restrict__ e_v, const float* __restrict__ e_t,
                const float* __restrict__ Wq,  const float* __restrict__ bq,
                const float* __restrict__ Wk_v, const float* __restrict__ bk_v,
                const float* __restrict__ Wk_t, const float* __restrict__ bk_t,
                const float* __restrict__ q0ws, float* __restrict__ out) {
    __shared__ float sAT[4][BK][PAD_AT];   // transposed input tiles [k][row]
    __shared__ float sW[3][BK][BN];        // weight tiles [k][col]
    __shared__ float sQ0[BN], sBq[BN], sBkv[BN], sBkt[BN];

    const int tid   = threadIdx.x;
    const int rbase = blockIdx.x * BM;
    const int rt = tid >> 4;               // 0..15 row-thread
    const int ct = tid & 15;               // 0..15 col-thread
    const int r0 = rt * 2;
    const int c0 = ct * 4;

    float pvv[2] = {0, 0}, pvt[2] = {0, 0}, ptv[2] = {0, 0}, ptt[2] = {0, 0};
    float pvb[2] = {0, 0}, ptb[2] = {0, 0}, pq0v[2] = {0, 0}, pq0t[2] = {0, 0};

    const int srow = tid >> 3;             // 0..31 staging row
    const int sk4  = (tid & 7) * 4;        // staging k-offset

    for (int ch = 0; ch < CHUNKS; ++ch) {
        const int cbase = ch * BN;
        __syncthreads();                   // protect bias buffers from prev chunk readers
        if (tid < 16) {
            *(float4*)(&sBq[tid * 4]) = *(const float4*)(bq + cbase + tid * 4);
        } else if (tid < 32) {
            *(float4*)(&sBkv[(tid - 16) * 4]) = *(const float4*)(bk_v + cbase + (tid - 16) * 4);
        } else if (tid < 48) {
            *(float4*)(&sBkt[(tid - 32) * 4]) = *(const float4*)(bk_t + cbase + (tid - 32) * 4);
        } else if (tid < 64) {
            *(float4*)(&sQ0[(tid - 48) * 4]) = *(const float4*)(q0ws + cbase + (tid - 48) * 4);
        }

        float aKv[2][4] = {}, aKt[2][4] = {}, aPv[2][4] = {}, aPt[2][4] = {};

        for (int kt = 0; kt < KTILES; ++kt) {
            const int kb = kt * BK;
            __syncthreads();
            {   // stage inputs, transposed into LDS
                const size_t goff = (size_t)(rbase + srow) * D_DIM + kb + sk4;
                const float4 v0 = *(const float4*)(x_v + goff);
                const float4 v1 = *(const float4*)(x_t + goff);
                const float4 v2 = *(const float4*)(e_v + goff);
                const float4 v3 = *(const float4*)(e_t + goff);
                sAT[0][sk4 + 0][srow] = v0.x; sAT[0][sk4 + 1][srow] = v0.y;
                sAT[0][sk4 + 2][srow] = v0.z; sAT[0][sk4 + 3][srow] = v0.w;
                sAT[1][sk4 + 0][srow] = v1.x; sAT[1][sk4 + 1][srow] = v1.y;
                sAT[1][sk4 + 2][srow] = v1.z; sAT[1][sk4 + 3][srow] = v1.w;
                sAT[2][sk4 + 0][srow] = v2.x; sAT[2][sk4 + 1][srow] = v2.y;
                sAT[2][sk4 + 2][srow] = v2.z; sAT[2][sk4 + 3][srow] = v2.w;
                sAT[3][sk4 + 0][srow] = v3.x; sAT[3][sk4 + 1][srow] = v3.y;
                sAT[3][sk4 + 2][srow] = v3.z; sAT[3][sk4 + 3][srow] = v3.w;
            }
#pragma unroll
            for (int p = 0; p < 2; ++p) {  // stage weights
                const int f  = p * 256 + tid;
                const int k  = f >> 4;
                const int c4 = (f & 15) * 4;
                const size_t gk = (size_t)(kb + k) * H_DIM + cbase + c4;
                *(float4*)(&sW[0][k][c4]) = *(const float4*)(Wk_v + gk);
                *(float4*)(&sW[1][k][c4]) = *(const float4*)(Wk_t + gk);
                *(float4*)(&sW[2][k][c4]) = *(const float4*)(Wq + gk);
            }
            __syncthreads();

// NOTE: parameter named W_ — a parameter named `w` makes `w.w` expand to
// `<arg>.<arg>` (both tokens substituted): that was Round 1's compile error.
#define FMA_ROW(acc, a, W_)                         \
    acc[0] = fmaf(a, W_.x, acc[0]);                 \
    acc[1] = fmaf(a, W_.y, acc[1]);                 \
    acc[2] = fmaf(a, W_.z, acc[2]);                 \
    acc[3] = fmaf(a, W_.w, acc[3]);

#pragma unroll 8
            for (int k = 0; k < BK; ++k) {
                const float2 av  = *(const float2*)(&sAT[0][k][r0]);
                const float2 at  = *(const float2*)(&sAT[1][k][r0]);
                const float2 aev = *(const float2*)(&sAT[2][k][r0]);
                const float2 aet = *(const float2*)(&sAT[3][k][r0]);
                const float4 wv  = *(const float4*)(&sW[0][k][c0]);
                const float4 wt  = *(const float4*)(&sW[1][k][c0]);
                const float4 wq  = *(const float4*)(&sW[2][k][c0]);
                FMA_ROW(aKv[0], av.x, wv); FMA_ROW(aKv[1], av.y, wv);
                FMA_ROW(aKt[0], at.x, wt); FMA_ROW(aKt[1], at.y, wt);
                FMA_ROW(aPv[0], aev.x, wq); FMA_ROW(aPv[1], aev.y, wq);
                FMA_ROW(aPt[0], aet.x, wq); FMA_ROW(aPt[1], aet.y, wq);
            }
        }

        // chunk epilogue: add key biases, accumulate the 8 per-row dot partials
        const float4 q0c = *(const float4*)(&sQ0[c0]);
        const float4 bqc = *(const float4*)(&sBq[c0]);
        const float4 bkv = *(const float4*)(&sBkv[c0]);
        const float4 bkt = *(const float4*)(&sBkt[c0]);
#pragma unroll
        for (int i = 0; i < 2; ++i) {
            const float kv0 = aKv[i][0] + bkv.x, kv1 = aKv[i][1] + bkv.y;
            const float kv2 = aKv[i][2] + bkv.z, kv3 = aKv[i][3] + bkv.w;
            const float kt0 = aKt[i][0] + bkt.x, kt1 = aKt[i][1] + bkt.y;
            const float kt2 = aKt[i][2] + bkt.z, kt3 = aKt[i][3] + bkt.w;
            pvv[i] += kv0 * aPv[i][0] + kv1 * aPv[i][1] + kv2 * aPv[i][2] + kv3 * aPv[i][3];
            pvt[i] += kv0 * aPt[i][0] + kv1 * aPt[i][1] + kv2 * aPt[i][2] + kv3 * aPt[i][3];
            ptv[i] += kt0 * aPv[i][0] + kt1 * aPv[i][1] + kt2 * aPv[i][2] + kt3 * aPv[i][3];
            ptt[i] += kt0 * aPt[i][0] + kt1 * aPt[i][1] + kt2 * aPt[i][2] + kt3 * aPt[i][3];
            pvb[i] += kv0 * bqc.x + kv1 * bqc.y + kv2 * bqc.z + kv3 * bqc.w;
            ptb[i] += kt0 * bqc.x + kt1 * bqc.y + kt2 * bqc.z + kt3 * bqc.w;
            pq0v[i] += kv0 * q0c.x + kv1 * q0c.y + kv2 * q0c.z + kv3 * q0c.w;
            pq0t[i] += kt0 * q0c.x + kt1 * q0c.y + kt2 * q0c.z + kt3 * q0c.w;
        }
    }

    // reduce across the 16 col-threads (contiguous 16-lane groups in a wave)
#pragma unroll
    for (int off = 8; off >= 1; off >>= 1) {
#pragma unroll
        for (int i = 0; i < 2; ++i) {
            pvv[i] += __shfl_xor(pvv[i], off);
            pvt[i] += __shfl_xor(pvt[i], off);
            ptv[i] += __shfl_xor(ptv[i], off);
            ptt[i] += __shfl_xor(ptt[i], off);
            pvb[i] += __shfl_xor(pvb[i], off);
            ptb[i] += __shfl_xor(ptb[i], off);
            pq0v[i] += __shfl_xor(pq0v[i], off);
            pq0t[i] += __shfl_xor(pq0t[i], off);
        }
    }

    if (ct == 0) {
#pragma unroll
        for (int i = 0; i < 2; ++i) {
            const int row = rbase + r0 + i;
            float dv = pq0v[i], dt = pq0t[i];
            float a0, a1;
#pragma unroll
            for (int s = 0; s <= 4; ++s) {
                if (s > 0) {
                    dv = a0 * pvv[i] + a1 * pvt[i] + pvb[i];
                    dt = a0 * ptv[i] + a1 * ptt[i] + ptb[i];
                }
                const float m  = fmaxf(dv, dt);
                const float ev = __expf(dv - m), et = __expf(dt - m);
                const float inv = 1.f / (ev + et);
                a0 = ev * inv; a1 = et * inv;
            }
            out[2 * row + 0] = a0;
            out[2 * row + 1] = a1;
        }
    }
}

extern "C" void kernel_launch(void* const* d_in, const int* in_sizes, int n_in,
                              void* d_out, int out_size, void* d_ws, size_t ws_size,
                              hipStream_t stream) {
    const float* x_v  = (const float*)d_in[0];
    const float* x_t  = (const float*)d_in[1];
    const float* e_v  = (const float*)d_in[2];
    const float* e_t  = (const float*)d_in[3];
    const float* gw0  = (const float*)d_in[4];
    const float* Wq   = (const float*)d_in[5];
    const float* bq   = (const float*)d_in[6];
    const float* Wk_v = (const float*)d_in[7];
    const float* bk_v = (const float*)d_in[8];
    const float* Wk_t = (const float*)d_in[9];
    const float* bk_t = (const float*)d_in[10];
    float* q0ws = (float*)d_ws;            // 512 floats
    float* out  = (float*)d_out;

    q0_kernel<<<32, 256, 0, stream>>>(gw0, Wq, bq, q0ws);
    dqa_kernel<<<B_ROWS / BM, 256, 0, stream>>>(x_v, x_t, e_v, e_t, Wq, bq,
                                                Wk_v, bk_v, Wk_t, bk_t, q0ws, out);
}

// Round 8
// 1106.171 us; speedup vs baseline: 3.1890x; 3.1890x over previous
//
#include <hip/hip_runtime.h>
#include <stdint.h>

#define B_ROWS 16384
#define D_DIM  2048
#define H_DIM  512
#define BM 64
#define BN 64
#define BK 32
#define CHUNKS 8
#define KTILES 64
#define NRB (B_ROWS / BM)     // 256 row-blocks; grid = 256*8 = 2048

typedef __attribute__((ext_vector_type(4))) float  f32x4;
typedef __attribute__((ext_vector_type(8))) __bf16 bf16x8;

// ---- LDS geometry (bytes). k-granule-major: [g][row] of 16B (8 bf16 = k g*8..g*8+7)
#define AST   1088                    // A per-g region stride (1024 + 64 pad -> 2-way writes)
#define AMAT  (4 * AST)               // per (mat,hilo) = 4352
#define A_TOTAL (8 * AMAT)            // 4 mats x 2 hilo = 34816
#define BST   1024
#define BMAT  (4 * BST)
#define B_OFF A_TOTAL
#define SMEM_BYTES (A_TOTAL + 6 * BMAT)   // 34816 + 24576 = 59392 (< 64K static)

// ws layout (floats): [0..511] q0 ; [512 .. 512+16384*8) scalar accum S[row][8]
#define WS_S 512

__device__ __forceinline__ uint32_t hibits(float x) {
    // round-to-nearest (ties away) to bf16, kept as masked fp32 bit pattern
    return (__float_as_uint(x) + 0x8000u) & 0xFFFF0000u;
}

// ---------------------------------------------------------------------------
__global__ void zero_kernel(float* __restrict__ S) {
    const int i = blockIdx.x * 256 + threadIdx.x;     // 32768 float4s
    ((float4*)S)[i] = make_float4(0.f, 0.f, 0.f, 0.f);
}

// q0 = gw0 @ Wq + bq -> ws[0..511]
__global__ void q0_kernel(const float* __restrict__ gw0, const float* __restrict__ Wq,
                          const float* __restrict__ bq, float* __restrict__ q0out) {
    __shared__ float red[256];
    const int c  = blockIdx.x * 16 + (threadIdx.x & 15);
    const int dq = threadIdx.x >> 4;
    float s = 0.f;
#pragma unroll 8
    for (int i = 0; i < 128; ++i) {
        const int d = dq * 128 + i;
        s = fmaf(gw0[d], Wq[(size_t)d * H_DIM + c], s);
    }
    red[threadIdx.x] = s;
    __syncthreads();
    if (threadIdx.x < 16) {
        float t = 0.f;
#pragma unroll
        for (int q = 0; q < 16; ++q) t += red[q * 16 + threadIdx.x];
        q0out[c] = t + bq[c];
    }
}

// ---------------------------------------------------------------------------
// Per (row-block, chunk): 4 GEMM tiles via split-bf16 MFMA, contract to 8
// per-row scalar partials, atomicAdd into S[row][8].
// ---------------------------------------------------------------------------
__global__ __launch_bounds__(256, 2)
void dqa_mfma(const float* __restrict__ x_v, const float* __restrict__ x_t,
              const float* __restrict__ e_v, const float* __restrict__ e_t,
              const float* __restrict__ Wq,  const float* __restrict__ bq,
              const float* __restrict__ Wk_v, const float* __restrict__ bk_v,
              const float* __restrict__ Wk_t, const float* __restrict__ bk_t,
              float* __restrict__ ws) {
    __shared__ char smem[SMEM_BYTES];

    const int tid   = threadIdx.x;
    const int rb    = blockIdx.x & (NRB - 1);
    const int ch    = blockIdx.x >> 8;            // 0..7
    const int rbase = rb * BM;
    const int cbase = ch * BN;

    const int lane = tid & 63;
    const int wv   = tid >> 6;                    // wave 0..3
    const int wm   = wv >> 1, wn = wv & 1;        // 2M x 2N
    const int l15  = lane & 15, lg = lane >> 4;   // frag col/row group, k-granule

    // staging assignments
    const int arow = tid >> 2, ag = tid & 3;      // A: 64 rows x 4 granules
    const int bcol = tid & 63, bg = tid >> 6;     // B: 64 cols x 4 granules

    const float* Amats[4] = {x_v, x_t, e_v, e_t};
    const float* Bmats[3] = {Wk_v, Wk_t, Wq};

    f32x4 acc[4][2][2];                           // [outmat][mrep][nrep]
#pragma unroll
    for (int m = 0; m < 4; ++m)
#pragma unroll
        for (int i = 0; i < 2; ++i)
#pragma unroll
            for (int j = 0; j < 2; ++j) acc[m][i][j] = (f32x4)0.f;

    // precomputed frag read offsets (lane-dependent parts)
    const int aro = lg * AST + (wm * 32 + l15) * 16;            // + mrep*256 + (mat*2+h)*AMAT
    const int bro = B_OFF + lg * BST + (wn * 32 + l15) * 16;    // + nrep*256 + (bmat*2+h)*BMAT

    for (int kt = 0; kt < KTILES; ++kt) {
        const int kb = kt * BK;
        __syncthreads();
        // ---- stage A (4 input mats): thread -> (arow, granule ag), 8 k-values
        {
            const size_t goff = (size_t)(rbase + arow) * D_DIM + kb + ag * 8;
            const int    aoff = ag * AST + arow * 16;
#pragma unroll
            for (int m = 0; m < 4; ++m) {
                const float4 v0 = *(const float4*)(Amats[m] + goff);
                const float4 v1 = *(const float4*)(Amats[m] + goff + 4);
                uint32_t h0 = hibits(v0.x), h1 = hibits(v0.y), h2 = hibits(v0.z), h3 = hibits(v0.w);
                uint32_t h4 = hibits(v1.x), h5 = hibits(v1.y), h6 = hibits(v1.z), h7 = hibits(v1.w);
                uint4 H;
                H.x = (h0 >> 16) | h1;  H.y = (h2 >> 16) | h3;
                H.z = (h4 >> 16) | h5;  H.w = (h6 >> 16) | h7;
                float l0 = v0.x - __uint_as_float(h0), l1 = v0.y - __uint_as_float(h1);
                float l2 = v0.z - __uint_as_float(h2), l3 = v0.w - __uint_as_float(h3);
                float l4 = v1.x - __uint_as_float(h4), l5 = v1.y - __uint_as_float(h5);
                float l6 = v1.z - __uint_as_float(h6), l7 = v1.w - __uint_as_float(h7);
                uint4 L;
                L.x = (hibits(l0) >> 16) | hibits(l1);  L.y = (hibits(l2) >> 16) | hibits(l3);
                L.z = (hibits(l4) >> 16) | hibits(l5);  L.w = (hibits(l6) >> 16) | hibits(l7);
                *(uint4*)(smem + (m * 2 + 0) * AMAT + aoff) = H;
                *(uint4*)(smem + (m * 2 + 1) * AMAT + aoff) = L;
            }
        }
        // ---- stage B (3 weight mats): thread -> (col bcol, granule bg), 8 k (strided)
        {
            const int boff = B_OFF + bg * BST + bcol * 16;
#pragma unroll
            for (int m = 0; m < 3; ++m) {
                const float* wp = Bmats[m] + (size_t)(kb + bg * 8) * H_DIM + cbase + bcol;
                float e0 = wp[0 * H_DIM], e1 = wp[1 * H_DIM], e2 = wp[2 * H_DIM], e3 = wp[3 * H_DIM];
                float e4 = wp[4 * H_DIM], e5 = wp[5 * H_DIM], e6 = wp[6 * H_DIM], e7 = wp[7 * H_DIM];
                uint32_t h0 = hibits(e0), h1 = hibits(e1), h2 = hibits(e2), h3 = hibits(e3);
                uint32_t h4 = hibits(e4), h5 = hibits(e5), h6 = hibits(e6), h7 = hibits(e7);
                uint4 H;
                H.x = (h0 >> 16) | h1;  H.y = (h2 >> 16) | h3;
                H.z = (h4 >> 16) | h5;  H.w = (h6 >> 16) | h7;
                float l0 = e0 - __uint_as_float(h0), l1 = e1 - __uint_as_float(h1);
                float l2 = e2 - __uint_as_float(h2), l3 = e3 - __uint_as_float(h3);
                float l4 = e4 - __uint_as_float(h4), l5 = e5 - __uint_as_float(h5);
                float l6 = e6 - __uint_as_float(h6), l7 = e7 - __uint_as_float(h7);
                uint4 L;
                L.x = (hibits(l0) >> 16) | hibits(l1);  L.y = (hibits(l2) >> 16) | hibits(l3);
                L.z = (hibits(l4) >> 16) | hibits(l5);  L.w = (hibits(l6) >> 16) | hibits(l7);
                *(uint4*)(smem + (m * 2 + 0) * BMAT + boff) = H;
                *(uint4*)(smem + (m * 2 + 1) * BMAT + boff) = L;
            }
        }
        __syncthreads();

        // ---- A fragments (held), B per nrep, 48 MFMAs
        bf16x8 af[4][2][2];                        // [mat][hilo][mrep]
#pragma unroll
        for (int m = 0; m < 4; ++m)
#pragma unroll
            for (int h = 0; h < 2; ++h)
#pragma unroll
                for (int mr = 0; mr < 2; ++mr)
                    af[m][h][mr] = __builtin_bit_cast(bf16x8,
                        *(const uint4*)(smem + (m * 2 + h) * AMAT + aro + mr * 256));

#pragma unroll
        for (int nr = 0; nr < 2; ++nr) {
            bf16x8 bfr[3][2];
#pragma unroll
            for (int m = 0; m < 3; ++m)
#pragma unroll
                for (int h = 0; h < 2; ++h)
                    bfr[m][h] = __builtin_bit_cast(bf16x8,
                        *(const uint4*)(smem + (m * 2 + h) * BMAT + bro + nr * 256));
#pragma unroll
            for (int m = 0; m < 4; ++m) {
                const int bmap = (m < 2) ? m : 2;
#pragma unroll
                for (int mr = 0; mr < 2; ++mr) {
                    f32x4 c = acc[m][mr][nr];
                    c = __builtin_amdgcn_mfma_f32_16x16x32_bf16(af[m][0][mr], bfr[bmap][0], c, 0, 0, 0);
                    c = __builtin_amdgcn_mfma_f32_16x16x32_bf16(af[m][0][mr], bfr[bmap][1], c, 0, 0, 0);
                    c = __builtin_amdgcn_mfma_f32_16x16x32_bf16(af[m][1][mr], bfr[bmap][0], c, 0, 0, 0);
                    acc[m][mr][nr] = c;
                }
            }
        }
    }

    // ---- epilogue: add key biases, form 8 per-row scalar partials, reduce, atomadd
    float bkvc[2], bktc[2], bqc[2], q0c[2];
#pragma unroll
    for (int nr = 0; nr < 2; ++nr) {
        const int col = cbase + wn * 32 + nr * 16 + l15;
        bkvc[nr] = bk_v[col];  bktc[nr] = bk_t[col];
        bqc[nr]  = bq[col];    q0c[nr]  = ws[col];    // q0 (includes bq)
    }
    float* S = ws + WS_S;
#pragma unroll
    for (int mr = 0; mr < 2; ++mr) {
#pragma unroll
        for (int r = 0; r < 4; ++r) {
            const float kv0 = acc[0][mr][0][r] + bkvc[0], kv1 = acc[0][mr][1][r] + bkvc[1];
            const float kt0 = acc[1][mr][0][r] + bktc[0], kt1 = acc[1][mr][1][r] + bktc[1];
            const float pv0 = acc[2][mr][0][r],           pv1 = acc[2][mr][1][r];
            const float pt0 = acc[3][mr][0][r],           pt1 = acc[3][mr][1][r];
            float s0 = kv0 * pv0 + kv1 * pv1;
            float s1 = kv0 * pt0 + kv1 * pt1;
            float s2 = kt0 * pv0 + kt1 * pv1;
            float s3 = kt0 * pt0 + kt1 * pt1;
            float s4 = kv0 * bqc[0] + kv1 * bqc[1];
            float s5 = kt0 * bqc[0] + kt1 * bqc[1];
            float s6 = kv0 * q0c[0] + kv1 * q0c[1];
            float s7 = kt0 * q0c[0] + kt1 * q0c[1];
#pragma unroll
            for (int off = 1; off <= 8; off <<= 1) {
                s0 += __shfl_xor(s0, off); s1 += __shfl_xor(s1, off);
                s2 += __shfl_xor(s2, off); s3 += __shfl_xor(s3, off);
                s4 += __shfl_xor(s4, off); s5 += __shfl_xor(s5, off);
                s6 += __shfl_xor(s6, off); s7 += __shfl_xor(s7, off);
            }
            if (l15 == 0) {
                const int row = rbase + wm * 32 + mr * 16 + lg * 4 + r;
                atomicAdd(&S[row * 8 + 0], s0); atomicAdd(&S[row * 8 + 1], s1);
                atomicAdd(&S[row * 8 + 2], s2); atomicAdd(&S[row * 8 + 3], s3);
                atomicAdd(&S[row * 8 + 4], s4); atomicAdd(&S[row * 8 + 5], s5);
                atomicAdd(&S[row * 8 + 6], s6); atomicAdd(&S[row * 8 + 7], s7);
            }
        }
    }
}

// ---------------------------------------------------------------------------
__global__ void final_kernel(const float* __restrict__ S, float* __restrict__ out) {
    const int row = blockIdx.x * 256 + threadIdx.x;
    const float* s = S + row * 8;
    const float svv = s[0], svt = s[1], stv = s[2], stt = s[3], svb = s[4], stb = s[5];
    float dv = s[6], dt = s[7];
    float a0 = 0.f, a1 = 0.f;
#pragma unroll
    for (int i = 0; i <= 4; ++i) {
        if (i) { dv = a0 * svv + a1 * svt + svb; dt = a0 * stv + a1 * stt + stb; }
        const float m  = fmaxf(dv, dt);
        const float ev = __expf(dv - m), et = __expf(dt - m);
        const float inv = 1.f / (ev + et);
        a0 = ev * inv; a1 = et * inv;
    }
    out[2 * row + 0] = a0;
    out[2 * row + 1] = a1;
}

extern "C" void kernel_launch(void* const* d_in, const int* in_sizes, int n_in,
                              void* d_out, int out_size, void* d_ws, size_t ws_size,
                              hipStream_t stream) {
    const float* x_v  = (const float*)d_in[0];
    const float* x_t  = (const float*)d_in[1];
    const float* e_v  = (const float*)d_in[2];
    const float* e_t  = (const float*)d_in[3];
    const float* gw0  = (const float*)d_in[4];
    const float* Wq   = (const float*)d_in[5];
    const float* bq   = (const float*)d_in[6];
    const float* Wk_v = (const float*)d_in[7];
    const float* bk_v = (const float*)d_in[8];
    const float* Wk_t = (const float*)d_in[9];
    const float* bk_t = (const float*)d_in[10];
    float* ws  = (float*)d_ws;    // [512 q0][16384*8 scalar accum] = 526 KB
    float* out = (float*)d_out;

    zero_kernel<<<128, 256, 0, stream>>>(ws + WS_S);
    q0_kernel<<<32, 256, 0, stream>>>(gw0, Wq, bq, ws);
    dqa_mfma<<<NRB * CHUNKS, 256, 0, stream>>>(x_v, x_t, e_v, e_t, Wq, bq,
                                               Wk_v, bk_v, Wk_t, bk_t, ws);
    final_kernel<<<B_ROWS / 256, 256, 0, stream>>>(ws + WS_S, out);
}